// Round 1
// baseline (313.060 us; speedup 1.0000x reference)
//
#include <hip/hip_runtime.h>
#include <stdint.h>

typedef __attribute__((ext_vector_type(8))) short bf16x8;
typedef __attribute__((ext_vector_type(4))) float f32x4;

#define CC 256
#define HWP 65536
#define NPIX 131072

__device__ __forceinline__ unsigned short f2bf(float f) {
    union { float f; unsigned int u; } v; v.f = f;
    unsigned int u = v.u;
    return (unsigned short)((u + 0x7fffu + ((u >> 16) & 1u)) >> 16);
}

__device__ __forceinline__ float sigm_relu(float xn) {
    float xr = fmaxf(xn, 0.f);
    float e = __expf(-xr);
    return __builtin_amdgcn_rcpf(1.f + e);
}

// ---- pass 1: per-channel partial sums over 256-pixel chunks ----
__global__ __launch_bounds__(256) void k1_part(const float* __restrict__ x,
                                               float* __restrict__ part) {
    int t = threadIdx.x, bid = blockIdx.x;
    const float* xp = x + (size_t)bid * 256 * CC + t;
    float s = 0.f, q = 0.f;
    #pragma unroll 8
    for (int p = 0; p < 256; ++p) { float v = xp[(size_t)p * CC]; s += v; q += v * v; }
    part[bid * 512 + t] = s;
    part[bid * 512 + 256 + t] = q;
}

// ---- pass 2: finalize mean / inv-std ----
__global__ __launch_bounds__(256) void k2_stats(const float* __restrict__ part,
                                                float* __restrict__ mg,
                                                float* __restrict__ ig) {
    int c = threadIdx.x;
    float s = 0.f, q = 0.f;
    #pragma unroll 4
    for (int i = 0; i < 512; ++i) { s += part[i * 512 + c]; q += part[i * 512 + 256 + c]; }
    float mean = s * (1.f / 131072.f);
    float var  = q * (1.f / 131072.f) - mean * mean;
    mg[c] = mean;
    ig[c] = rsqrtf(var + 1e-5f);
}

// ---- pass 3: Gram partials of y = w_down @ sigmoid(relu(xn)), sample 0 ----
__global__ __launch_bounds__(256) void k3_gram(const float* __restrict__ x,
                                               const float* __restrict__ wd,
                                               const float* __restrict__ mg,
                                               const float* __restrict__ ig,
                                               float* __restrict__ gpart) {
    __shared__ float wd_s[16 * 257];
    __shared__ float a_s[256];
    __shared__ float y_s[16];
    const int t = threadIdx.x;
    for (int i = t; i < 4096; i += 256) wd_s[(i >> 8) * 257 + (i & 255)] = wd[i];
    const float mean = mg[t], istd = ig[t];
    const int o1 = t >> 4, j = t & 15;
    const float* xp = x + (size_t)blockIdx.x * 64 * CC + t;
    float gacc = 0.f;
    __syncthreads();
    for (int p = 0; p < 64; ++p) {
        float xn = (xp[(size_t)p * CC] - mean) * istd;
        a_s[t] = sigm_relu(xn);
        __syncthreads();
        float partial = 0.f;
        #pragma unroll
        for (int i = 0; i < 16; ++i)
            partial += wd_s[o1 * 257 + j + 16 * i] * a_s[j + 16 * i];
        partial += __shfl_xor(partial, 1);
        partial += __shfl_xor(partial, 2);
        partial += __shfl_xor(partial, 4);
        partial += __shfl_xor(partial, 8);
        if (j == 0) y_s[o1] = partial;
        __syncthreads();
        gacc += y_s[o1] * y_s[j];
    }
    gpart[blockIdx.x * 256 + t] = gacc;
}

// ---- pass 4: reduce G partials, R = G0 @ w_down  (16 x 256) ----
__global__ __launch_bounds__(256) void k4_R(const float* __restrict__ gpart,
                                            const float* __restrict__ wd,
                                            float* __restrict__ Rg) {
    __shared__ float G_s[256];
    const int t = threadIdx.x;
    float g = 0.f;
    #pragma unroll 8
    for (int i = 0; i < 1024; ++i) g += gpart[i * 256 + t];
    G_s[t] = g;
    __syncthreads();
    #pragma unroll
    for (int o = 0; o < 16; ++o) {
        float r = 0.f;
        #pragma unroll
        for (int o2 = 0; o2 < 16; ++o2) r += G_s[o * 16 + o2] * wd[o2 * 256 + t];
        Rg[o * 256 + t] = r;
    }
}

// ---- pass 5: Wcb = [ Wf1 | (Wf2 @ w_up) @ R ]  in bf16, 256 x 512 ----
__global__ __launch_bounds__(256) void k5_wcb(const float* __restrict__ wf,
                                              const float* __restrict__ wu,
                                              const float* __restrict__ Rg,
                                              unsigned short* __restrict__ wcb) {
    __shared__ float M_s[16][17];
    const int t = threadIdx.x;
    const int lr = t >> 4, j = t & 15;
    const int r = blockIdx.x * 16 + lr;
    const float* wfr = wf + (size_t)r * 512;
    float m = 0.f;
    for (int c = 0; c < 256; ++c) m += wfr[256 + c] * wu[c * 16 + j];
    M_s[lr][j] = m;
    __syncthreads();
    float Ml[16];
    #pragma unroll
    for (int o = 0; o < 16; ++o) Ml[o] = M_s[lr][o];
    unsigned short* wrow = wcb + (size_t)r * 512;
    for (int i = 0; i < 16; ++i) {
        int c = j + 16 * i;
        wrow[c] = f2bf(wfr[c]);
        float kv = 0.f;
        #pragma unroll
        for (int o = 0; o < 16; ++o) kv += Ml[o] * Rg[o * 256 + c];
        wrow[256 + c] = f2bf(kv);
    }
}

// ---- pass 6: out = Wcb @ [xn; a], MFMA bf16, 64 pixels / block ----
__global__ __launch_bounds__(256) void k6_main(const float* __restrict__ x,
                                               const unsigned short* __restrict__ wcb,
                                               const float* __restrict__ mg,
                                               const float* __restrict__ ig,
                                               float* __restrict__ out) {
    __shared__ unsigned short zpack[32768];  // [kb 0..63][n^kb 0..63][8] bf16 octets
    const int t = threadIdx.x, bid = blockIdx.x;
    const int b = bid >> 10;
    const int p0 = (bid & 1023) * 64;

    // producer: stage [xn; a] for 64 pixels as bf16 k-octets
    {
        const int kb = t & 31, c0 = kb * 8, nb = t >> 5;
        float4 m0 = *(const float4*)(mg + c0), m1 = *(const float4*)(mg + c0 + 4);
        float4 i0 = *(const float4*)(ig + c0), i1 = *(const float4*)(ig + c0 + 4);
        float mm[8] = {m0.x,m0.y,m0.z,m0.w,m1.x,m1.y,m1.z,m1.w};
        float ii[8] = {i0.x,i0.y,i0.z,i0.w,i1.x,i1.y,i1.z,i1.w};
        uint4* zw = (uint4*)zpack;
        #pragma unroll
        for (int rep = 0; rep < 8; ++rep) {
            int n = rep * 8 + nb;
            const float4* xp = (const float4*)(x + ((size_t)(b * HWP + p0 + n)) * CC + c0);
            float4 v0 = xp[0], v1 = xp[1];
            float vv[8] = {v0.x,v0.y,v0.z,v0.w,v1.x,v1.y,v1.z,v1.w};
            unsigned int xw[4], aw[4];
            #pragma unroll
            for (int h = 0; h < 4; ++h) {
                float xn0 = (vv[2*h]   - mm[2*h])   * ii[2*h];
                float xn1 = (vv[2*h+1] - mm[2*h+1]) * ii[2*h+1];
                float a0 = sigm_relu(xn0), a1 = sigm_relu(xn1);
                xw[h] = (unsigned)f2bf(xn0) | ((unsigned)f2bf(xn1) << 16);
                aw[h] = (unsigned)f2bf(a0)  | ((unsigned)f2bf(a1)  << 16);
            }
            uint4 px = {xw[0],xw[1],xw[2],xw[3]};
            uint4 pa = {aw[0],aw[1],aw[2],aw[3]};
            zw[kb * 64 + (n ^ kb)] = px;
            zw[(kb + 32) * 64 + (n ^ (kb + 32))] = pa;
        }
    }
    __syncthreads();

    // consumer: wave w -> output rows [w*64, w*64+64), all 64 pixels
    const int w = t >> 6, l = t & 63, lm = l & 15, lk = l >> 4;
    f32x4 acc[4][4];
    #pragma unroll
    for (int mt = 0; mt < 4; ++mt)
        #pragma unroll
        for (int nt = 0; nt < 4; ++nt)
            acc[mt][nt] = (f32x4){0.f, 0.f, 0.f, 0.f};
    const uint4* zr = (const uint4*)zpack;
    #pragma unroll 2
    for (int kt = 0; kt < 16; ++kt) {
        bf16x8 afr[4], bfr[4];
        #pragma unroll
        for (int mt = 0; mt < 4; ++mt) {
            int row = w * 64 + mt * 16 + lm;
            afr[mt] = *(const bf16x8*)(wcb + (size_t)row * 512 + kt * 32 + lk * 8);
        }
        #pragma unroll
        for (int nt = 0; nt < 4; ++nt) {
            int kb = kt * 4 + lk;
            int n = nt * 16 + lm;
            uint4 u = zr[kb * 64 + (n ^ kb)];
            bfr[nt] = *(bf16x8*)&u;
        }
        #pragma unroll
        for (int mt = 0; mt < 4; ++mt)
            #pragma unroll
            for (int nt = 0; nt < 4; ++nt)
                acc[mt][nt] = __builtin_amdgcn_mfma_f32_16x16x32_bf16(afr[mt], bfr[nt], acc[mt][nt], 0, 0, 0);
    }
    // epilogue: D row = (lane>>4)*4 + reg, col = lane&15
    #pragma unroll
    for (int mt = 0; mt < 4; ++mt) {
        int rowb = w * 64 + mt * 16 + lk * 4;
        #pragma unroll
        for (int i = 0; i < 4; ++i) {
            float* op = out + ((size_t)(b * 256 + rowb + i)) * HWP + p0 + lm;
            #pragma unroll
            for (int nt = 0; nt < 4; ++nt)
                op[nt * 16] = acc[mt][nt][i];
        }
    }
}

extern "C" void kernel_launch(void* const* d_in, const int* in_sizes, int n_in,
                              void* d_out, int out_size, void* d_ws, size_t ws_size,
                              hipStream_t stream) {
    const float* x  = (const float*)d_in[0];
    const float* wd = (const float*)d_in[1];
    const float* wu = (const float*)d_in[2];
    const float* wf = (const float*)d_in[3];
    float* out = (float*)d_out;
    char* ws = (char*)d_ws;
    unsigned short* wcb = (unsigned short*)ws;                       // 256 KiB
    float* part  = (float*)(ws + 262144);                            // 1 MiB
    float* mg    = (float*)(ws + 262144 + 1048576);                  // 1 KiB
    float* ig    = (float*)(ws + 262144 + 1048576 + 1024);           // 1 KiB
    float* gpart = (float*)(ws + 262144 + 1048576 + 2048);           // 1 MiB
    float* Rg    = (float*)(ws + 262144 + 2097152 + 2048);           // 16 KiB

    k1_part<<<dim3(512), dim3(256), 0, stream>>>(x, part);
    k2_stats<<<dim3(1), dim3(256), 0, stream>>>(part, mg, ig);
    k3_gram<<<dim3(1024), dim3(256), 0, stream>>>(x, wd, mg, ig, gpart);
    k4_R<<<dim3(1), dim3(256), 0, stream>>>(gpart, wd, Rg);
    k5_wcb<<<dim3(16), dim3(256), 0, stream>>>(wf, wu, Rg, wcb);
    k6_main<<<dim3(2048), dim3(256), 0, stream>>>(x, wcb, mg, ig, out);
}

// Round 2
// 224.945 us; speedup vs baseline: 1.3917x; 1.3917x over previous
//
#include <hip/hip_runtime.h>
#include <stdint.h>

typedef __attribute__((ext_vector_type(8))) short bf16x8;
typedef __attribute__((ext_vector_type(4))) float f32x4;

#define CC 256
#define HWP 65536

__device__ __forceinline__ unsigned short f2bf(float f) {
    union { float f; unsigned int u; } v; v.f = f;
    unsigned int u = v.u;
    return (unsigned short)((u + 0x7fffu + ((u >> 16) & 1u)) >> 16);
}

__device__ __forceinline__ float sigm_relu(float xn) {
    float xr = fmaxf(xn, 0.f);
    float e = __expf(-xr);
    return __builtin_amdgcn_rcpf(1.f + e);
}

// ---- k1: per-channel partial sums over 256-pixel chunks ----
__global__ __launch_bounds__(256) void k1_part(const float* __restrict__ x,
                                               float* __restrict__ part) {
    int t = threadIdx.x, bid = blockIdx.x;
    const float* xp = x + (size_t)bid * 256 * CC + t;
    float s = 0.f, q = 0.f;
    #pragma unroll 8
    for (int p = 0; p < 256; ++p) { float v = xp[(size_t)p * CC]; s += v; q += v * v; }
    part[bid * 512 + t] = s;
    part[bid * 512 + 256 + t] = q;
}

// ---- k2a: reduce 512 partial rows -> 32 rows ----
__global__ __launch_bounds__(256) void k2a_red(const float* __restrict__ part,
                                               float* __restrict__ p2) {
    int t = threadIdx.x, r = blockIdx.x;
    float s = 0.f, q = 0.f;
    #pragma unroll
    for (int i = 0; i < 16; ++i) {
        s += part[(size_t)(r * 16 + i) * 512 + t];
        q += part[(size_t)(r * 16 + i) * 512 + 256 + t];
    }
    p2[r * 512 + t] = s;
    p2[r * 512 + 256 + t] = q;
}

// ---- k2b: finalize mean / inv-std ----
__global__ __launch_bounds__(256) void k2b_stats(const float* __restrict__ p2,
                                                 float* __restrict__ mg,
                                                 float* __restrict__ ig) {
    int c = threadIdx.x;
    float s = 0.f, q = 0.f;
    #pragma unroll
    for (int r = 0; r < 32; ++r) { s += p2[r * 512 + c]; q += p2[r * 512 + 256 + c]; }
    float mean = s * (1.f / 131072.f);
    float var  = q * (1.f / 131072.f) - mean * mean;
    mg[c] = mean;
    ig[c] = rsqrtf(var + 1e-5f);
}

// ---- k3: Gram partials of y = w_down @ sigmoid(relu(xn)), sample 0 ----
// 1024 blocks x 64 px; wd rows in registers; a_s padded-swizzled float4 reads;
// 4 px per barrier pair; x prefetch.
#define PR 284
__global__ __launch_bounds__(256) void k3_gram(const float* __restrict__ x,
                                               const float* __restrict__ wd,
                                               const float* __restrict__ mg,
                                               const float* __restrict__ ig,
                                               float* __restrict__ gpart) {
    __shared__ float a_s[4 * PR];
    __shared__ float y_s[4][16];
    const int t = threadIdx.x;
    const int o1 = t >> 4, j = t & 15;
    float wdr[16];
    #pragma unroll
    for (int i = 0; i < 16; ++i) wdr[i] = wd[o1 * 256 + j * 16 + i];
    const float mean = mg[t], istd = ig[t];
    const float* xp = x + (size_t)blockIdx.x * 64 * CC + t;
    const int wph = t + ((t >> 5) << 2);            // swizzled write slot
    const int rbase = j * 16 + ((j >> 1) << 2);      // swizzled read base
    float gacc = 0.f;
    float c0 = xp[0], c1 = xp[CC], c2 = xp[2 * CC], c3 = xp[3 * CC];
    for (int it = 0; it < 16; ++it) {
        float n0 = 0.f, n1 = 0.f, n2 = 0.f, n3 = 0.f;
        if (it < 15) {
            const float* xq = xp + (size_t)(it * 4 + 4) * CC;
            n0 = xq[0]; n1 = xq[CC]; n2 = xq[2 * CC]; n3 = xq[3 * CC];
        }
        a_s[0 * PR + wph] = sigm_relu((c0 - mean) * istd);
        a_s[1 * PR + wph] = sigm_relu((c1 - mean) * istd);
        a_s[2 * PR + wph] = sigm_relu((c2 - mean) * istd);
        a_s[3 * PR + wph] = sigm_relu((c3 - mean) * istd);
        __syncthreads();
        #pragma unroll
        for (int p = 0; p < 4; ++p) {
            float prt = 0.f;
            #pragma unroll
            for (int q = 0; q < 4; ++q) {
                float4 av = *(const float4*)&a_s[p * PR + rbase + q * 4];
                prt += wdr[q * 4 + 0] * av.x + wdr[q * 4 + 1] * av.y
                     + wdr[q * 4 + 2] * av.z + wdr[q * 4 + 3] * av.w;
            }
            prt += __shfl_xor(prt, 1);
            prt += __shfl_xor(prt, 2);
            prt += __shfl_xor(prt, 4);
            prt += __shfl_xor(prt, 8);
            if (j == 0) y_s[p][o1] = prt;
        }
        __syncthreads();
        #pragma unroll
        for (int p = 0; p < 4; ++p) gacc += y_s[p][o1] * y_s[p][j];
        c0 = n0; c1 = n1; c2 = n2; c3 = n3;
    }
    gpart[blockIdx.x * 256 + t] = gacc;
}

// ---- k4a: reduce 1024 Gram partial rows -> 64 ----
__global__ __launch_bounds__(256) void k4a_red(const float* __restrict__ gpart,
                                               float* __restrict__ g2) {
    int t = threadIdx.x, r = blockIdx.x;
    float g = 0.f;
    #pragma unroll
    for (int i = 0; i < 16; ++i) g += gpart[(size_t)(r * 16 + i) * 256 + t];
    g2[r * 256 + t] = g;
}

// ---- k4b: final G reduce + R = G0 @ w_down ----
__global__ __launch_bounds__(256) void k4b_R(const float* __restrict__ g2,
                                             const float* __restrict__ wd,
                                             float* __restrict__ Rg) {
    __shared__ float G_s[256];
    const int t = threadIdx.x;
    float g = 0.f;
    #pragma unroll
    for (int i = 0; i < 64; ++i) g += g2[i * 256 + t];
    G_s[t] = g;
    __syncthreads();
    #pragma unroll
    for (int o = 0; o < 16; ++o) {
        float r = 0.f;
        #pragma unroll
        for (int o2 = 0; o2 < 16; ++o2) r += G_s[o * 16 + o2] * wd[o2 * 256 + t];
        Rg[o * 256 + t] = r;
    }
}

// ---- k5: Wcb = [ Wf1 | (Wf2 @ w_up) @ R ]  in bf16, 256 x 512 ----
__global__ __launch_bounds__(256) void k5_wcb(const float* __restrict__ wf,
                                              const float* __restrict__ wu,
                                              const float* __restrict__ Rg,
                                              unsigned short* __restrict__ wcb) {
    __shared__ float M_s[16][17];
    const int t = threadIdx.x;
    const int lr = t >> 4, j = t & 15;
    const int r = blockIdx.x * 16 + lr;
    const float* wfr = wf + (size_t)r * 512;
    float m = 0.f;
    for (int c = 0; c < 256; ++c) m += wfr[256 + c] * wu[c * 16 + j];
    M_s[lr][j] = m;
    __syncthreads();
    float Ml[16];
    #pragma unroll
    for (int o = 0; o < 16; ++o) Ml[o] = M_s[lr][o];
    unsigned short* wrow = wcb + (size_t)r * 512;
    for (int i = 0; i < 16; ++i) {
        int c = j + 16 * i;
        wrow[c] = f2bf(wfr[c]);
        float kv = 0.f;
        #pragma unroll
        for (int o = 0; o < 16; ++o) kv += Ml[o] * Rg[o * 256 + c];
        wrow[256 + c] = f2bf(kv);
    }
}

// ---- k6: out = [xn; a] x Wcb^T via MFMA (D = [pixel][channel]), pipelined ----
__global__ __launch_bounds__(256, 2) void k6_main(const float* __restrict__ x,
                                                  const unsigned short* __restrict__ wcb,
                                                  const float* __restrict__ mg,
                                                  const float* __restrict__ ig,
                                                  float* __restrict__ out) {
    __shared__ unsigned short zpack[32768];  // [kb 0..63][n^kb][8] bf16
    const int t = threadIdx.x;
    const int tile0 = blockIdx.x * 4;        // 4 tiles of 64 px per block
    const int b = tile0 >> 10;               // sample (never split within block)
    // producer mapping
    const int kb = t & 31, c0 = kb * 8, nb = t >> 5;
    float4 m0 = *(const float4*)(mg + c0), m1 = *(const float4*)(mg + c0 + 4);
    float4 i0 = *(const float4*)(ig + c0), i1 = *(const float4*)(ig + c0 + 4);
    const float mm[8] = {m0.x, m0.y, m0.z, m0.w, m1.x, m1.y, m1.z, m1.w};
    const float ii[8] = {i0.x, i0.y, i0.z, i0.w, i1.x, i1.y, i1.z, i1.w};
    // consumer mapping: wave w owns 64 channel rows; lm = channel-in-16, lk = k/px quad
    const int w = t >> 6, lm = t & 15, lk = (t >> 4) & 3;
    const unsigned short* wrow = wcb + (size_t)(w * 64 + lm) * 512 + lk * 8;
    float* outw = out + (size_t)(b * 256 + w * 64 + lm) * HWP;

    float4 sA[8], sB[8];

#define LOADT(PW) do { \
        const float* xb = x + ((size_t)(b * HWP + (PW) + nb)) * CC + c0; \
        _Pragma("unroll") \
        for (int rep = 0; rep < 8; ++rep) { \
            sA[rep] = *(const float4*)(xb + (size_t)rep * 8 * CC); \
            sB[rep] = *(const float4*)(xb + (size_t)rep * 8 * CC + 4); \
        } } while (0)

#define CONV() do { \
        uint4* zw = (uint4*)zpack; \
        _Pragma("unroll") \
        for (int rep = 0; rep < 8; ++rep) { \
            int n = rep * 8 + nb; \
            float vv[8] = {sA[rep].x, sA[rep].y, sA[rep].z, sA[rep].w, \
                           sB[rep].x, sB[rep].y, sB[rep].z, sB[rep].w}; \
            unsigned int xw[4], aw[4]; \
            _Pragma("unroll") \
            for (int h = 0; h < 4; ++h) { \
                float xn0 = (vv[2 * h]     - mm[2 * h])     * ii[2 * h]; \
                float xn1 = (vv[2 * h + 1] - mm[2 * h + 1]) * ii[2 * h + 1]; \
                float a0 = sigm_relu(xn0), a1 = sigm_relu(xn1); \
                xw[h] = (unsigned)f2bf(xn0) | ((unsigned)f2bf(xn1) << 16); \
                aw[h] = (unsigned)f2bf(a0)  | ((unsigned)f2bf(a1)  << 16); \
            } \
            uint4 px4 = {xw[0], xw[1], xw[2], xw[3]}; \
            uint4 pa4 = {aw[0], aw[1], aw[2], aw[3]}; \
            zw[kb * 64 + (n ^ kb)] = px4; \
            zw[(kb + 32) * 64 + (n ^ (kb + 32))] = pa4; \
        } } while (0)

    int pw0 = (tile0 & 1023) * 64;
    LOADT(pw0);
    CONV();
    __syncthreads();

    for (int i = 0; i < 4; ++i) {
        const int pw = pw0 + i * 64;
        if (i < 3) LOADT(pw + 64);   // issue next tile's loads; stay in flight under MFMA

        f32x4 acc[4][4];
        #pragma unroll
        for (int mt = 0; mt < 4; ++mt)
            #pragma unroll
            for (int nt = 0; nt < 4; ++nt) acc[mt][nt] = (f32x4){0.f, 0.f, 0.f, 0.f};
        const uint4* zr = (const uint4*)zpack;
        #pragma unroll 2
        for (int kt = 0; kt < 16; ++kt) {
            bf16x8 zfr[4], wfr[4];
            const int kbr = kt * 4 + lk;
            #pragma unroll
            for (int mt = 0; mt < 4; ++mt) {
                uint4 u = zr[kbr * 64 + ((mt * 16 + lm) ^ kbr)];
                zfr[mt] = *(bf16x8*)&u;
            }
            #pragma unroll
            for (int nt = 0; nt < 4; ++nt)
                wfr[nt] = *(const bf16x8*)(wrow + (size_t)nt * 16 * 512 + kt * 32);
            #pragma unroll
            for (int mt = 0; mt < 4; ++mt)
                #pragma unroll
                for (int nt = 0; nt < 4; ++nt)
                    acc[mt][nt] = __builtin_amdgcn_mfma_f32_16x16x32_bf16(
                        zfr[mt], wfr[nt], acc[mt][nt], 0, 0, 0);
        }
        // D[m=pixel][n=channel]: lane holds px quad lk*4+0..3 for channel lm -> float4 stores
        #pragma unroll
        for (int nt = 0; nt < 4; ++nt)
            #pragma unroll
            for (int mt = 0; mt < 4; ++mt)
                *(f32x4*)(outw + (size_t)nt * 16 * HWP + pw + mt * 16 + lk * 4) = acc[mt][nt];
        __syncthreads();
        if (i < 3) { CONV(); __syncthreads(); }
    }
#undef LOADT
#undef CONV
}

extern "C" void kernel_launch(void* const* d_in, const int* in_sizes, int n_in,
                              void* d_out, int out_size, void* d_ws, size_t ws_size,
                              hipStream_t stream) {
    const float* x  = (const float*)d_in[0];
    const float* wd = (const float*)d_in[1];
    const float* wu = (const float*)d_in[2];
    const float* wf = (const float*)d_in[3];
    float* out = (float*)d_out;
    char* ws = (char*)d_ws;
    unsigned short* wcb = (unsigned short*)ws;               // 256 KiB
    float* part  = (float*)(ws + 262144);                    // 1 MiB
    float* p2    = (float*)(ws + 262144 + 1048576);          // 64 KiB
    float* mg    = (float*)(ws + 1376256);                   // 1 KiB
    float* ig    = (float*)(ws + 1377280);                   // 1 KiB
    float* gpart = (float*)(ws + 1378304);                   // 1 MiB
    float* g2    = (float*)(ws + 2426880);                   // 64 KiB
    float* Rg    = (float*)(ws + 2492416);                   // 16 KiB

    k1_part <<<dim3(512),  dim3(256), 0, stream>>>(x, part);
    k2a_red <<<dim3(32),   dim3(256), 0, stream>>>(part, p2);
    k2b_stats<<<dim3(1),   dim3(256), 0, stream>>>(p2, mg, ig);
    k3_gram <<<dim3(1024), dim3(256), 0, stream>>>(x, wd, mg, ig, gpart);
    k4a_red <<<dim3(64),   dim3(256), 0, stream>>>(gpart, g2);
    k4b_R   <<<dim3(1),    dim3(256), 0, stream>>>(g2, wd, Rg);
    k5_wcb  <<<dim3(16),   dim3(256), 0, stream>>>(wf, wu, Rg, wcb);
    k6_main <<<dim3(512),  dim3(256), 0, stream>>>(x, wcb, mg, ig, out);
}

// Round 3
// 184.986 us; speedup vs baseline: 1.6923x; 1.2160x over previous
//
#include <hip/hip_runtime.h>
#include <stdint.h>

typedef __attribute__((ext_vector_type(8))) short bf16x8;
typedef __attribute__((ext_vector_type(4))) float f32x4;

#define CC 256
#define HWP 65536

__device__ __forceinline__ unsigned short f2bf(float f) {
    union { float f; unsigned int u; } v; v.f = f;
    unsigned int u = v.u;
    return (unsigned short)((u + 0x7fffu + ((u >> 16) & 1u)) >> 16);
}
__device__ __forceinline__ unsigned int f2bf2(float lo, float hi) {
    return (unsigned)f2bf(lo) | ((unsigned)f2bf(hi) << 16);
}
__device__ __forceinline__ float sigm_relu(float xn) {
    float xr = fmaxf(xn, 0.f);
    float e = __expf(-xr);
    return __builtin_amdgcn_rcpf(1.f + e);
}

// ---- k1: per-channel partial sums, float4 loads + LDS pixel-group reduce ----
__global__ __launch_bounds__(256) void k1_part(const float* __restrict__ x,
                                               float* __restrict__ part) {
    __shared__ float red[4][520];
    const int t = threadIdx.x, bid = blockIdx.x;
    const int c4 = (t & 63) * 4, po = t >> 6;
    const float* xp = x + ((size_t)(bid * 256 + po)) * CC + c4;
    f32x4 s = {0.f, 0.f, 0.f, 0.f}, q = {0.f, 0.f, 0.f, 0.f};
    #pragma unroll 8
    for (int p = 0; p < 64; ++p) {
        f32x4 v = *(const f32x4*)(xp + (size_t)p * 4 * CC);
        s += v; q += v * v;
    }
    *(f32x4*)&red[po][c4] = s;
    *(f32x4*)&red[po][256 + c4] = q;
    __syncthreads();
    part[bid * 512 + t]       = red[0][t] + red[1][t] + red[2][t] + red[3][t];
    part[bid * 512 + 256 + t] = red[0][256 + t] + red[1][256 + t] + red[2][256 + t] + red[3][256 + t];
}

// ---- k2a: reduce 512 partial rows -> 32 rows ----
__global__ __launch_bounds__(256) void k2a_red(const float* __restrict__ part,
                                               float* __restrict__ p2) {
    int t = threadIdx.x, r = blockIdx.x;
    float s = 0.f, q = 0.f;
    #pragma unroll
    for (int i = 0; i < 16; ++i) {
        s += part[(size_t)(r * 16 + i) * 512 + t];
        q += part[(size_t)(r * 16 + i) * 512 + 256 + t];
    }
    p2[r * 512 + t] = s;
    p2[r * 512 + 256 + t] = q;
}

// ---- k2b: finalize mean / inv-std ----
__global__ __launch_bounds__(256) void k2b_stats(const float* __restrict__ p2,
                                                 float* __restrict__ mg,
                                                 float* __restrict__ ig) {
    int c = threadIdx.x;
    float s = 0.f, q = 0.f;
    #pragma unroll
    for (int r = 0; r < 32; ++r) { s += p2[r * 512 + c]; q += p2[r * 512 + 256 + c]; }
    float mean = s * (1.f / 131072.f);
    float var  = q * (1.f / 131072.f) - mean * mean;
    mg[c] = mean;
    ig[c] = rsqrtf(var + 1e-5f);
}

// ---- k3: Gram via MFMA. Y = wd@a (bf16), G-partial = Y Y^T (fp32) ----
__global__ __launch_bounds__(256) void k3_gram(const float* __restrict__ x,
                                               const float* __restrict__ wd,
                                               const float* __restrict__ mg,
                                               const float* __restrict__ ig,
                                               float* __restrict__ gpart) {
    __shared__ uint4 apack[2048];        // [kb 0..31][n^kb 0..63] bf16 octets, 32KB
    __shared__ float y_s[16][68];
    const int t = threadIdx.x;
    const int w = t >> 6, lm = t & 15, lk = (t >> 4) & 3;
    // wd A-fragments (8 k-steps over K=256), bf16 in regs
    uint4 wfrag[8];
    #pragma unroll
    for (int kt = 0; kt < 8; ++kt) {
        const int kbr = kt * 4 + lk;
        f32x4 wa = *(const f32x4*)(wd + lm * 256 + kbr * 8);
        f32x4 wb = *(const f32x4*)(wd + lm * 256 + kbr * 8 + 4);
        wfrag[kt] = (uint4){f2bf2(wa[0], wa[1]), f2bf2(wa[2], wa[3]),
                            f2bf2(wb[0], wb[1]), f2bf2(wb[2], wb[3])};
    }
    // producer: a = sigmoid(relu(xn)) bf16 octets for 64 px (sample 0)
    {
        const int kb = t & 31, c0 = kb * 8, nb = t >> 5;
        f32x4 m0 = *(const f32x4*)(mg + c0), m1 = *(const f32x4*)(mg + c0 + 4);
        f32x4 i0 = *(const f32x4*)(ig + c0), i1 = *(const f32x4*)(ig + c0 + 4);
        float mm[8] = {m0[0],m0[1],m0[2],m0[3],m1[0],m1[1],m1[2],m1[3]};
        float ii[8] = {i0[0],i0[1],i0[2],i0[3],i1[0],i1[1],i1[2],i1[3]};
        #pragma unroll
        for (int rep = 0; rep < 8; ++rep) {
            int n = rep * 8 + nb;
            const float* xp = x + ((size_t)(blockIdx.x * 64 + n)) * CC + c0;
            f32x4 v0 = *(const f32x4*)xp;
            f32x4 v1 = *(const f32x4*)(xp + 4);
            float vv[8] = {v0[0],v0[1],v0[2],v0[3],v1[0],v1[1],v1[2],v1[3]};
            unsigned aw[4];
            #pragma unroll
            for (int h = 0; h < 4; ++h) {
                float a0 = sigm_relu((vv[2*h]   - mm[2*h])   * ii[2*h]);
                float a1 = sigm_relu((vv[2*h+1] - mm[2*h+1]) * ii[2*h+1]);
                aw[h] = f2bf2(a0, a1);
            }
            apack[kb * 64 + (n ^ kb)] = (uint4){aw[0], aw[1], aw[2], aw[3]};
        }
    }
    __syncthreads();
    // Y[o][px]: wave w -> px tile w*16..+16
    f32x4 accY = {0.f, 0.f, 0.f, 0.f};
    #pragma unroll
    for (int kt = 0; kt < 8; ++kt) {
        const int kbr = kt * 4 + lk;
        uint4 u = apack[kbr * 64 + ((w * 16 + lm) ^ kbr)];
        accY = __builtin_amdgcn_mfma_f32_16x16x32_bf16(*(bf16x8*)&wfrag[kt], *(bf16x8*)&u, accY, 0, 0, 0);
    }
    #pragma unroll
    for (int i = 0; i < 4; ++i) y_s[lk * 4 + i][w * 16 + lm] = accY[i];
    __syncthreads();
    // G-partial: thread (o1,o2) sums over 64 px in fp32
    const int o1 = t >> 4, o2 = t & 15;
    float g = 0.f;
    #pragma unroll
    for (int p4 = 0; p4 < 16; ++p4) {
        f32x4 ya = *(const f32x4*)&y_s[o1][p4 * 4];
        f32x4 yb = *(const f32x4*)&y_s[o2][p4 * 4];
        g += ya[0]*yb[0] + ya[1]*yb[1] + ya[2]*yb[2] + ya[3]*yb[3];
    }
    gpart[blockIdx.x * 256 + t] = g;
}

// ---- k4a: reduce 1024 Gram partial rows -> 64 ----
__global__ __launch_bounds__(256) void k4a_red(const float* __restrict__ gpart,
                                               float* __restrict__ g2) {
    int t = threadIdx.x, r = blockIdx.x;
    float g = 0.f;
    #pragma unroll
    for (int i = 0; i < 16; ++i) g += gpart[(size_t)(r * 16 + i) * 256 + t];
    g2[r * 256 + t] = g;
}

// ---- k4b: final G reduce + R = G0 @ w_down ----
__global__ __launch_bounds__(256) void k4b_R(const float* __restrict__ g2,
                                             const float* __restrict__ wd,
                                             float* __restrict__ Rg) {
    __shared__ float G_s[256];
    const int t = threadIdx.x;
    float g = 0.f;
    #pragma unroll
    for (int i = 0; i < 64; ++i) g += g2[i * 256 + t];
    G_s[t] = g;
    __syncthreads();
    #pragma unroll
    for (int o = 0; o < 16; ++o) {
        float r = 0.f;
        #pragma unroll
        for (int o2 = 0; o2 < 16; ++o2) r += G_s[o * 16 + o2] * wd[o2 * 256 + t];
        Rg[o * 256 + t] = r;
    }
}

// ---- k5: Wcb = [ Wf1 | (Wf2 @ w_up) @ R ]  in bf16, 256 x 512 ----
__global__ __launch_bounds__(256) void k5_wcb(const float* __restrict__ wf,
                                              const float* __restrict__ wu,
                                              const float* __restrict__ Rg,
                                              unsigned short* __restrict__ wcb) {
    __shared__ float M_s[16][17];
    const int t = threadIdx.x;
    const int lr = t >> 4, j = t & 15;
    const int r = blockIdx.x * 16 + lr;
    const float* wfr = wf + (size_t)r * 512;
    float m = 0.f;
    for (int c = 0; c < 256; ++c) m += wfr[256 + c] * wu[c * 16 + j];
    M_s[lr][j] = m;
    __syncthreads();
    float Ml[16];
    #pragma unroll
    for (int o = 0; o < 16; ++o) Ml[o] = M_s[lr][o];
    unsigned short* wrow = wcb + (size_t)r * 512;
    for (int i = 0; i < 16; ++i) {
        int c = j + 16 * i;
        wrow[c] = f2bf(wfr[c]);
        float kv = 0.f;
        #pragma unroll
        for (int o = 0; o < 16; ++o) kv += Ml[o] * Rg[o * 256 + c];
        wrow[256 + c] = f2bf(kv);
    }
}

// ---- k6: out = z x Wcb^T, 512 threads / 64 px / block, convert-once LDS ----
__global__ __launch_bounds__(512, 4) void k6_main(const float* __restrict__ x,
                                                  const unsigned short* __restrict__ wcb,
                                                  const float* __restrict__ mg,
                                                  const float* __restrict__ ig,
                                                  float* __restrict__ out) {
    __shared__ uint4 zpack[4096];   // [r 0..63][n^r 0..63] bf16 octets, 64KB
    const int t = threadIdx.x;
    const int tile = blockIdx.x;
    const int b = tile >> 10;
    const int pw = (tile & 1023) * 64;
    // producer: stage z=[xn;a] for 64 px
    {
        const int kb = t & 31, c0 = kb * 8, nb = t >> 5;  // nb 0..15
        f32x4 m0 = *(const f32x4*)(mg + c0), m1 = *(const f32x4*)(mg + c0 + 4);
        f32x4 i0 = *(const f32x4*)(ig + c0), i1 = *(const f32x4*)(ig + c0 + 4);
        float mm[8] = {m0[0],m0[1],m0[2],m0[3],m1[0],m1[1],m1[2],m1[3]};
        float ii[8] = {i0[0],i0[1],i0[2],i0[3],i1[0],i1[1],i1[2],i1[3]};
        const float* xb = x + ((size_t)(b * HWP + pw + nb)) * CC + c0;
        #pragma unroll
        for (int rep = 0; rep < 4; ++rep) {
            int n = rep * 16 + nb;
            const float* xp = xb + (size_t)rep * 16 * CC;
            f32x4 v0 = *(const f32x4*)xp;
            f32x4 v1 = *(const f32x4*)(xp + 4);
            float vv[8] = {v0[0],v0[1],v0[2],v0[3],v1[0],v1[1],v1[2],v1[3]};
            unsigned xw[4], aw[4];
            #pragma unroll
            for (int h = 0; h < 4; ++h) {
                float xn0 = (vv[2*h]   - mm[2*h])   * ii[2*h];
                float xn1 = (vv[2*h+1] - mm[2*h+1]) * ii[2*h+1];
                xw[h] = f2bf2(xn0, xn1);
                aw[h] = f2bf2(sigm_relu(xn0), sigm_relu(xn1));
            }
            zpack[kb * 64 + (n ^ kb)] = (uint4){xw[0], xw[1], xw[2], xw[3]};
            zpack[(kb + 32) * 64 + (n ^ (kb + 32))] = (uint4){aw[0], aw[1], aw[2], aw[3]};
        }
    }
    __syncthreads();
    // consumer: wave w -> 32 channel rows, 64 px
    const int w = t >> 6, lm = t & 15, lk = (t >> 4) & 3;
    const unsigned short* wrow = wcb + (size_t)(w * 32 + lm) * 512 + lk * 8;
    float* outw = out + ((size_t)(b * 256 + w * 32 + lm)) * HWP + pw;
    f32x4 acc[4][2];
    #pragma unroll
    for (int mt = 0; mt < 4; ++mt)
        #pragma unroll
        for (int nt = 0; nt < 2; ++nt) acc[mt][nt] = (f32x4){0.f, 0.f, 0.f, 0.f};
    #pragma unroll 4
    for (int kt = 0; kt < 16; ++kt) {
        const int kbr = kt * 4 + lk;
        bf16x8 zfr[4], wfr[2];
        #pragma unroll
        for (int mt = 0; mt < 4; ++mt) {
            uint4 u = zpack[kbr * 64 + ((mt * 16 + lm) ^ kbr)];
            zfr[mt] = *(bf16x8*)&u;
        }
        #pragma unroll
        for (int nt = 0; nt < 2; ++nt)
            wfr[nt] = *(const bf16x8*)(wrow + (size_t)nt * 16 * 512 + kt * 32);
        #pragma unroll
        for (int mt = 0; mt < 4; ++mt)
            #pragma unroll
            for (int nt = 0; nt < 2; ++nt)
                acc[mt][nt] = __builtin_amdgcn_mfma_f32_16x16x32_bf16(zfr[mt], wfr[nt], acc[mt][nt], 0, 0, 0);
    }
    #pragma unroll
    for (int nt = 0; nt < 2; ++nt)
        #pragma unroll
        for (int mt = 0; mt < 4; ++mt)
            __builtin_nontemporal_store(acc[mt][nt],
                (f32x4*)(outw + (size_t)nt * 16 * HWP + mt * 16 + lk * 4));
}

extern "C" void kernel_launch(void* const* d_in, const int* in_sizes, int n_in,
                              void* d_out, int out_size, void* d_ws, size_t ws_size,
                              hipStream_t stream) {
    const float* x  = (const float*)d_in[0];
    const float* wd = (const float*)d_in[1];
    const float* wu = (const float*)d_in[2];
    const float* wf = (const float*)d_in[3];
    float* out = (float*)d_out;
    char* ws = (char*)d_ws;
    unsigned short* wcb = (unsigned short*)ws;               // 256 KiB
    float* part  = (float*)(ws + 262144);                    // 1 MiB
    float* p2    = (float*)(ws + 262144 + 1048576);          // 64 KiB
    float* mg    = (float*)(ws + 1376256);                   // 1 KiB
    float* ig    = (float*)(ws + 1377280);                   // 1 KiB
    float* gpart = (float*)(ws + 1378304);                   // 1 MiB
    float* g2    = (float*)(ws + 2426880);                   // 64 KiB
    float* Rg    = (float*)(ws + 2492416);                   // 16 KiB

    k1_part <<<dim3(512),  dim3(256), 0, stream>>>(x, part);
    k2a_red <<<dim3(32),   dim3(256), 0, stream>>>(part, p2);
    k2b_stats<<<dim3(1),   dim3(256), 0, stream>>>(p2, mg, ig);
    k3_gram <<<dim3(1024), dim3(256), 0, stream>>>(x, wd, mg, ig, gpart);
    k4a_red <<<dim3(64),   dim3(256), 0, stream>>>(gpart, g2);
    k4b_R   <<<dim3(1),    dim3(256), 0, stream>>>(g2, wd, Rg);
    k5_wcb  <<<dim3(16),   dim3(256), 0, stream>>>(wf, wu, Rg, wcb);
    k6_main <<<dim3(2048), dim3(512), 0, stream>>>(x, wcb, mg, ig, out);
}